// Round 14
// baseline (143.752 us; speedup 1.0000x reference)
//
#include <hip/hip_runtime.h>

#define E_TOT 500000
#define N_NODES 100000
#define NUNITS_H 3125   // 32-row units per half (3125*32 = 100000)
#define SRD 128         // blocks per half (grid 256)

typedef __attribute__((ext_vector_type(16))) float f32x16;
typedef __attribute__((ext_vector_type(8))) short short8;
typedef __attribute__((ext_vector_type(4))) float f32x4;

__device__ __forceinline__ unsigned short f2bf(float f) {
  union { float f; unsigned u; } x; x.f = f;
  unsigned r = x.u + 0x7fffu + ((x.u >> 16) & 1u);
  return (unsigned short)(r >> 16);
}

__device__ __forceinline__ float bf2f(unsigned short s) {
  union { unsigned u; float f; } x; x.u = ((unsigned)s) << 16;
  return x.f;
}

// Barrier that does NOT drain vmcnt: LDS-visibility only.
__device__ __forceinline__ void lds_barrier() {
  asm volatile("s_waitcnt lgkmcnt(0)" ::: "memory");
  __builtin_amdgcn_s_barrier();
}

// w1 (f32 [256][512]) -> w1r2 bf16 [half][kseg=0..31][n=0..255][j=0..7]
__global__ void k_repack_w1h(const float* __restrict__ w1,
                             unsigned short* __restrict__ w1r2) {
  int o = blockIdx.x * 256 + threadIdx.x;  // 131072 total
  int half = o >> 16;
  int kb = (o >> 11) & 31;
  int n = (o >> 3) & 255;
  int j = o & 7;
  w1r2[o] = f2bf(w1[n * 512 + half * 256 + kb * 8 + j]);
}

// U'[n] = zsrc[n] @ W1s^T + b1 (half 0) ; V[n] = zdst[n] @ W1d^T (half 1)
// v14: v13 + counted-wait barriers (no vmcnt drain) -> prefetch/stores live
// across barriers. B frags in AGPRs; depth-3 A pipeline; 1 barrier/unit.
__global__ __launch_bounds__(512, 1) void k_node_gemm(
    const float* __restrict__ zsrc, const float* __restrict__ zdst,
    const unsigned short* __restrict__ w1r2, const float* __restrict__ b1,
    unsigned short* __restrict__ Uo, unsigned short* __restrict__ Vo) {
  __shared__ __align__(16) unsigned short Ap[2][8192];  // 2 x 16 KB
  __shared__ __align__(16) unsigned short Ct[2][8192];  // 2 x 16 KB

  const int half = blockIdx.x >> 7;   // 128 blocks per half
  const int bh = blockIdx.x & 127;
  const float* Z = half ? zdst : zsrc;
  unsigned short* O = half ? Vo : Uo;

  const unsigned tid = threadIdx.x;
  const unsigned l = tid & 63u;
  const unsigned wv = tid >> 6;     // wave 0..7 -> cols wv*32..wv*32+31
  const unsigned l31 = l & 31u;
  const unsigned hi = l >> 5;
  const unsigned arow = tid & 31u;  // A-staging row
  const unsigned ak2 = tid >> 5;    // A-staging 16-float granule (0..15)

  // ---- B fragments: 16 x short8, loaded once (parked in AGPRs) ----
  short8 brg[16];
  {
    const unsigned short* bb = w1r2 + (unsigned)half * 65536u;
#pragma unroll
    for (int k = 0; k < 16; ++k) {
      unsigned ks = (unsigned)k * 2u + hi;
      brg[k] = *(const short8*)(bb + (ks * 256u + wv * 32u + l31) * 8u);
      asm volatile("" : "+v"(brg[k]));  // opacity: no re-materialization
    }
  }

  const float bi = half ? 0.f : b1[wv * 32u + l31];

  f32x4 apA[4], apB[4], apC[4];  // 3 pending A units (16 regs each)

#define LOAD_A(uu, ap_)                                                   \
  {                                                                       \
    int uc_ = (uu); if (uc_ >= NUNITS_H) uc_ = NUNITS_H - 1;              \
    const f32x4* p_ =                                                     \
        (const f32x4*)(Z + ((long)uc_ * 32 + arow) * 256 + ak2 * 16u);    \
    ap_[0] = p_[0]; ap_[1] = p_[1]; ap_[2] = p_[2]; ap_[3] = p_[3];       \
  }
#define WRITE_A(ap_, bf_)                                                 \
  {                                                                       \
    _Pragma("unroll") for (int g = 0; g < 2; ++g) {                       \
      short8 sa;                                                          \
      sa[0] = (short)f2bf(ap_[2*g].x);   sa[1] = (short)f2bf(ap_[2*g].y); \
      sa[2] = (short)f2bf(ap_[2*g].z);   sa[3] = (short)f2bf(ap_[2*g].w); \
      sa[4] = (short)f2bf(ap_[2*g+1].x); sa[5] = (short)f2bf(ap_[2*g+1].y); \
      sa[6] = (short)f2bf(ap_[2*g+1].z); sa[7] = (short)f2bf(ap_[2*g+1].w); \
      *(short8*)&Ap[bf_][((2u*ak2 + (unsigned)g)*32u + arow)*8u] = sa;    \
    }                                                                     \
  }

// one unit: issue A(u+3S) into NEW, compute Ap[cur], stage WR (=A(u+S)),
// counted-wait barrier, full-line stores (fire-and-forget).
#define BODY(uu, NEW, WR)                                                 \
  {                                                                       \
    LOAD_A((uu) + 3 * SRD, NEW);                                          \
    __builtin_amdgcn_sched_barrier(0);                                    \
    f32x16 acc = {0.f, 0.f, 0.f, 0.f, 0.f, 0.f, 0.f, 0.f,                 \
                  0.f, 0.f, 0.f, 0.f, 0.f, 0.f, 0.f, 0.f};                \
    _Pragma("unroll") for (int kk = 0; kk < 16; ++kk) {                   \
      unsigned ks = 2u * (unsigned)kk + hi;                               \
      short8 af = *(const short8*)&Ap[cur][(ks * 32u + l31) * 8u];        \
      acc = __builtin_amdgcn_mfma_f32_32x32x16_bf16(af, brg[kk], acc, 0, 0, 0); \
    }                                                                     \
    _Pragma("unroll") for (int r = 0; r < 16; ++r) {                      \
      unsigned row32 = (unsigned)((r & 3) + 8 * (r >> 2)) + 4u * hi;      \
      Ct[cur][row32 * 256u + wv * 32u + l31] = f2bf(acc[r] + bi);         \
    }                                                                     \
    WRITE_A(WR, cur ^ 1);                                                 \
    lds_barrier();                                                        \
    {                                                                     \
      const long gbase = (long)(uu) * 32 * 256;                           \
      _Pragma("unroll") for (int p = 0; p < 2; ++p) {                     \
        unsigned s = (unsigned)p * 512u + tid;                            \
        unsigned row = s >> 5;                                            \
        unsigned seg = s & 31u;                                           \
        short8 vv = *(const short8*)&Ct[cur][row * 256u + seg * 8u];      \
        *(short8*)(O + gbase + row * 256u + seg * 8u) = vv;               \
      }                                                                   \
    }                                                                     \
    cur ^= 1;                                                             \
  }

  int u = bh;
  int cur = 0;
  // prologue: A(u) -> LDS now; A(u+S), A(u+2S) in flight
  LOAD_A(u, apA);
  WRITE_A(apA, 0);
  LOAD_A(u + SRD, apB);
  LOAD_A(u + 2 * SRD, apC);
  lds_barrier();

  // rotation: (NEW,WR) = (A,B), (B,C), (C,A)
  for (; u < NUNITS_H;) {
    BODY(u, apA, apB);
    u += SRD;
    if (u >= NUNITS_H) break;
    BODY(u, apB, apC);
    u += SRD;
    if (u >= NUNITS_H) break;
    BODY(u, apC, apA);
    u += SRD;
  }
#undef BODY
#undef LOAD_A
#undef WRITE_A
}

// per edge: out = sigmoid( w2 . relu(U'[row] + V[col]) + b2 )
// 3-stage pipeline: idx(e+2) || rows(e+1) || compute(e)
#define EK_ITER 16
__global__ __launch_bounds__(256, 6) void k_edge(
    const unsigned short* __restrict__ U, const unsigned short* __restrict__ V,
    const int* __restrict__ eli, const float* __restrict__ w2,
    const float* __restrict__ b2, float* __restrict__ out) {
  const int tid = threadIdx.x;
  const int g = tid >> 4;
  const int j = tid & 15;
  float w2v[16];
#pragma unroll
  for (int q = 0; q < 8; ++q) {
    w2v[q] = w2[8 * j + q];
    w2v[8 + q] = w2[128 + 8 * j + q];
  }
  const float b2v = b2[0];
  const long base = (long)blockIdx.x * (16 * EK_ITER) + g;

#define CLAMP_E(k) \
  (((base + 16 * (k)) < E_TOT) ? (base + 16 * (k)) : (long)(E_TOT - 1))

  long eP = CLAMP_E(0);
  int rA = eli[eP], cA = eli[E_TOT + eP];
  long eQ = CLAMP_E(1);
  int rB = eli[eQ], cB = eli[E_TOT + eQ];
  short8 uA0 = *(const short8*)(U + (long)rA * 256 + 8 * j);
  short8 uA1 = *(const short8*)(U + (long)rA * 256 + 128 + 8 * j);
  short8 vA0 = *(const short8*)(V + (long)cA * 256 + 8 * j);
  short8 vA1 = *(const short8*)(V + (long)cA * 256 + 128 + 8 * j);
  short8 uB0, uB1, vB0, vB1;

#pragma unroll
  for (int it2 = 0; it2 < EK_ITER / 2; ++it2) {
    {
      long eN = CLAMP_E(2 * it2 + 2);
      int rN = eli[eN], cN = eli[E_TOT + eN];
      uB0 = *(const short8*)(U + (long)rB * 256 + 8 * j);
      uB1 = *(const short8*)(U + (long)rB * 256 + 128 + 8 * j);
      vB0 = *(const short8*)(V + (long)cB * 256 + 8 * j);
      vB1 = *(const short8*)(V + (long)cB * 256 + 128 + 8 * j);
      rB = rN; cB = cN;
      float p = 0.f;
#pragma unroll
      for (int q = 0; q < 8; ++q) {
        float a0 = bf2f((unsigned short)uA0[q]) + bf2f((unsigned short)vA0[q]);
        float a1 = bf2f((unsigned short)uA1[q]) + bf2f((unsigned short)vA1[q]);
        p = fmaf(fmaxf(a0, 0.f), w2v[q], p);
        p = fmaf(fmaxf(a1, 0.f), w2v[8 + q], p);
      }
      p += __shfl_xor(p, 1);
      p += __shfl_xor(p, 2);
      p += __shfl_xor(p, 4);
      p += __shfl_xor(p, 8);
      long e = base + 16 * (2 * it2);
      if (j == 0 && e < E_TOT) out[e] = 1.f / (1.f + __expf(-(p + b2v)));
    }
    {
      long eN = CLAMP_E(2 * it2 + 3);
      int rN = eli[eN], cN = eli[E_TOT + eN];
      uA0 = *(const short8*)(U + (long)rB * 256 + 8 * j);
      uA1 = *(const short8*)(U + (long)rB * 256 + 128 + 8 * j);
      vA0 = *(const short8*)(V + (long)cB * 256 + 8 * j);
      vA1 = *(const short8*)(V + (long)cB * 256 + 128 + 8 * j);
      rB = rN; cB = cN;
      float p = 0.f;
#pragma unroll
      for (int q = 0; q < 8; ++q) {
        float a0 = bf2f((unsigned short)uB0[q]) + bf2f((unsigned short)vB0[q]);
        float a1 = bf2f((unsigned short)uB1[q]) + bf2f((unsigned short)vB1[q]);
        p = fmaf(fmaxf(a0, 0.f), w2v[q], p);
        p = fmaf(fmaxf(a1, 0.f), w2v[8 + q], p);
      }
      p += __shfl_xor(p, 1);
      p += __shfl_xor(p, 2);
      p += __shfl_xor(p, 4);
      p += __shfl_xor(p, 8);
      long e = base + 16 * (2 * it2 + 1);
      if (j == 0 && e < E_TOT) out[e] = 1.f / (1.f + __expf(-(p + b2v)));
    }
  }
#undef CLAMP_E
}

extern "C" void kernel_launch(void* const* d_in, const int* in_sizes, int n_in,
                              void* d_out, int out_size, void* d_ws,
                              size_t ws_size, hipStream_t stream) {
  const float* zsrc = (const float*)d_in[0];
  const float* zdst = (const float*)d_in[1];
  const int* eli = (const int*)d_in[2];
  const float* w1 = (const float*)d_in[3];
  const float* b1 = (const float*)d_in[4];
  const float* w2 = (const float*)d_in[5];
  const float* b2 = (const float*)d_in[6];
  float* out = (float*)d_out;

  const size_t uv_bytes = (size_t)N_NODES * 256 * 2;  // 51.2 MB each
  unsigned short* U = (unsigned short*)d_ws;
  unsigned short* V = (unsigned short*)((char*)d_ws + uv_bytes);
  unsigned short* w1r2 = (unsigned short*)((char*)d_ws + 2 * uv_bytes);

  k_repack_w1h<<<512, 256, 0, stream>>>(w1, w1r2);
  k_node_gemm<<<256, 512, 0, stream>>>(zsrc, zdst, w1r2, b1, U, V);
  int nbe = (E_TOT + 16 * EK_ITER - 1) / (16 * EK_ITER);
  k_edge<<<nbe, 256, 0, stream>>>(U, V, eli, w2, b2, out);
}

// Round 16
// 139.412 us; speedup vs baseline: 1.0311x; 1.0311x over previous
//
#include <hip/hip_runtime.h>
#include <hip/hip_bf16.h>

#define E_TOT 500000
#define N_NODES 100000
#define NUNITS_H 3125   // 32-row units per half (3125*32 = 100000)
#define SRD 256         // blocks per half (grid 512)

typedef __attribute__((ext_vector_type(16))) float f32x16;
typedef __attribute__((ext_vector_type(8))) short short8;
typedef __attribute__((ext_vector_type(4))) float f32x4;

__device__ __forceinline__ unsigned short f2bf(float f) {
  union { float f; unsigned u; } x; x.f = f;
  unsigned r = x.u + 0x7fffu + ((x.u >> 16) & 1u);
  return (unsigned short)(r >> 16);
}

__device__ __forceinline__ float bf2f(unsigned short s) {
  union { unsigned u; float f; } x; x.u = ((unsigned)s) << 16;
  return x.f;
}

__device__ __forceinline__ short cvt1(float f) {
  __hip_bfloat16 h = __float2bfloat16(f);  // RNE; pairs fuse to v_cvt_pk
  union { __hip_bfloat16 h; short s; } u; u.h = h;
  return u.s;
}

__device__ __forceinline__ void gl_lds16(const void* g, void* l) {
  __builtin_amdgcn_global_load_lds(
      (const __attribute__((address_space(1))) void*)g,
      (__attribute__((address_space(3))) void*)l, 16, 0, 0);
}

// w1 (f32 [256][512]) -> w1r2 bf16 [half][kseg=0..31][n=0..255][j=0..7]
__global__ void k_repack_w1h(const float* __restrict__ w1,
                             unsigned short* __restrict__ w1r2) {
  int o = blockIdx.x * 256 + threadIdx.x;  // 131072 total
  int half = o >> 16;
  int kb = (o >> 11) & 31;
  int n = (o >> 3) & 255;
  int j = o & 7;
  w1r2[o] = f2bf(w1[n * 512 + half * 256 + kb * 8 + j]);
}

// U'[n] = zsrc[n] @ W1s^T + b1 (half 0) ; V[n] = zdst[n] @ W1d^T (half 1)
// v15b: A staged f32 via global_load_lds (pre-swizzled source, XOR-swizzled
// reads); cvt at consume; B frags in AGPRs; low VGPR -> 2 blocks/CU overlap.
__global__ __launch_bounds__(512, 2) void k_node_gemm(
    const float* __restrict__ zsrc, const float* __restrict__ zdst,
    const unsigned short* __restrict__ w1r2, const float* __restrict__ b1,
    unsigned short* __restrict__ Uo, unsigned short* __restrict__ Vo) {
  // 80 KB exactly: A f32 double-buffer 2x32KB + Ct 16KB -> 2 blocks/CU
  __shared__ __align__(16) char smem[81920];
  unsigned short* Ct = (unsigned short*)(smem + 65536);

  const int half = blockIdx.x >> 8;   // 256 blocks per half
  const int bh = blockIdx.x & 255;
  const float* Z = half ? zdst : zsrc;
  unsigned short* O = half ? Vo : Uo;

  const unsigned tid = threadIdx.x;
  const unsigned l = tid & 63u;
  const unsigned wv = tid >> 6;   // wave 0..7 -> cols wv*32..wv*32+31
  const unsigned l31 = l & 31u;
  const unsigned hi = l >> 5;
  const unsigned xr = (l31 & 7u) << 4;  // read-side XOR swizzle

  // ---- B fragments: 16 x short8, loaded once (parked in AGPRs) ----
  short8 brg[16];
  {
    const unsigned short* bb = w1r2 + (unsigned)half * 65536u;
#pragma unroll
    for (int k = 0; k < 16; ++k) {
      unsigned ks = (unsigned)k * 2u + hi;
      brg[k] = *(const short8*)(bb + (ks * 256u + wv * 32u + l31) * 8u);
      asm volatile("" : "+v"(brg[k]));  // opacity: no re-materialization
    }
  }

  const float bi = half ? 0.f : b1[wv * 32u + l31];

  // Stage unit uu (32 rows x 1KB f32, contiguous) into buffer bf.
  // Source pre-swizzled: LDS[row*1024+d] = global[row*1024+(d^((row&7)<<4))]
#define STAGE(uu, bf)                                                     \
  {                                                                       \
    int uc_ = (uu); if (uc_ >= NUNITS_H) uc_ = NUNITS_H - 1;              \
    const char* src_ = (const char*)(Z + (long)uc_ * 32 * 256);           \
    char* dst_ = smem + (unsigned)(bf)*32768u;                            \
    _Pragma("unroll") for (int q = 0; q < 4; ++q) {                       \
      unsigned row_ = wv * 4u + (unsigned)q;                              \
      unsigned off_ = row_ * 1024u;                                       \
      unsigned so_ = off_ + ((l * 16u) ^ ((row_ & 7u) << 4));             \
      gl_lds16(src_ + so_, dst_ + off_);                                  \
    }                                                                     \
  }

  int u = bh;
  int cur = 0;
  STAGE(u, 0);
  asm volatile("s_waitcnt vmcnt(0)" ::: "memory");
  __builtin_amdgcn_s_barrier();

  for (; u < NUNITS_H; u += SRD) {
    STAGE(u + SRD, cur ^ 1);            // in flight across whole unit
    __builtin_amdgcn_sched_barrier(0);  // pin: don't sink past compute

    const char* Ab = smem + (unsigned)cur * 32768u;
    f32x16 acc = {0.f, 0.f, 0.f, 0.f, 0.f, 0.f, 0.f, 0.f,
                  0.f, 0.f, 0.f, 0.f, 0.f, 0.f, 0.f, 0.f};
#pragma unroll
    for (int kk = 0; kk < 16; ++kk) {
      unsigned c0 = (unsigned)kk * 64u + hi * 32u;
      f32x4 a0 = *(const f32x4*)(Ab + l31 * 1024u + (c0 ^ xr));
      f32x4 a1 = *(const f32x4*)(Ab + l31 * 1024u + ((c0 + 16u) ^ xr));
      short8 af;
      af[0] = cvt1(a0.x); af[1] = cvt1(a0.y);
      af[2] = cvt1(a0.z); af[3] = cvt1(a0.w);
      af[4] = cvt1(a1.x); af[5] = cvt1(a1.y);
      af[6] = cvt1(a1.z); af[7] = cvt1(a1.w);
      acc = __builtin_amdgcn_mfma_f32_32x32x16_bf16(af, brg[kk], acc, 0, 0, 0);
    }

    // C tile: bias + cast, then barrier (Ct visible, stage(u+SRD) drained)
#pragma unroll
    for (int r = 0; r < 16; ++r) {
      unsigned row32 = (unsigned)((r & 3) + 8 * (r >> 2)) + 4u * hi;
      Ct[row32 * 256u + wv * 32u + l31] = f2bf(acc[r] + bi);
    }
    asm volatile("s_waitcnt vmcnt(0) lgkmcnt(0)" ::: "memory");
    __builtin_amdgcn_s_barrier();

    // full-line stores (fire-and-forget; drain overlaps next unit)
    {
      const long gbase = (long)u * 32 * 256;
#pragma unroll
      for (int p = 0; p < 2; ++p) {
        unsigned s = (unsigned)p * 512u + tid;
        unsigned row = s >> 5;
        unsigned seg = s & 31u;
        short8 vv = *(const short8*)&Ct[row * 256u + seg * 8u];
        *(short8*)(O + gbase + row * 256u + seg * 8u) = vv;
      }
    }
    // Ct consumed at store issue; sync before next unit's Ct writes
    __builtin_amdgcn_s_barrier();
    cur ^= 1;
  }
#undef STAGE
}

// per edge: out = sigmoid( w2 . relu(U'[row] + V[col]) + b2 )
// 3-stage pipeline: idx(e+2) || rows(e+1) || compute(e)
#define EK_ITER 16
__global__ __launch_bounds__(256, 6) void k_edge(
    const unsigned short* __restrict__ U, const unsigned short* __restrict__ V,
    const int* __restrict__ eli, const float* __restrict__ w2,
    const float* __restrict__ b2, float* __restrict__ out) {
  const int tid = threadIdx.x;
  const int g = tid >> 4;
  const int j = tid & 15;
  float w2v[16];
#pragma unroll
  for (int q = 0; q < 8; ++q) {
    w2v[q] = w2[8 * j + q];
    w2v[8 + q] = w2[128 + 8 * j + q];
  }
  const float b2v = b2[0];
  const long base = (long)blockIdx.x * (16 * EK_ITER) + g;

#define CLAMP_E(k) \
  (((base + 16 * (k)) < E_TOT) ? (base + 16 * (k)) : (long)(E_TOT - 1))

  long eP = CLAMP_E(0);
  int rA = eli[eP], cA = eli[E_TOT + eP];
  long eQ = CLAMP_E(1);
  int rB = eli[eQ], cB = eli[E_TOT + eQ];
  short8 uA0 = *(const short8*)(U + (long)rA * 256 + 8 * j);
  short8 uA1 = *(const short8*)(U + (long)rA * 256 + 128 + 8 * j);
  short8 vA0 = *(const short8*)(V + (long)cA * 256 + 8 * j);
  short8 vA1 = *(const short8*)(V + (long)cA * 256 + 128 + 8 * j);
  short8 uB0, uB1, vB0, vB1;

#pragma unroll
  for (int it2 = 0; it2 < EK_ITER / 2; ++it2) {
    {
      long eN = CLAMP_E(2 * it2 + 2);
      int rN = eli[eN], cN = eli[E_TOT + eN];
      uB0 = *(const short8*)(U + (long)rB * 256 + 8 * j);
      uB1 = *(const short8*)(U + (long)rB * 256 + 128 + 8 * j);
      vB0 = *(const short8*)(V + (long)cB * 256 + 8 * j);
      vB1 = *(const short8*)(V + (long)cB * 256 + 128 + 8 * j);
      rB = rN; cB = cN;
      float p = 0.f;
#pragma unroll
      for (int q = 0; q < 8; ++q) {
        float a0 = bf2f((unsigned short)uA0[q]) + bf2f((unsigned short)vA0[q]);
        float a1 = bf2f((unsigned short)uA1[q]) + bf2f((unsigned short)vA1[q]);
        p = fmaf(fmaxf(a0, 0.f), w2v[q], p);
        p = fmaf(fmaxf(a1, 0.f), w2v[8 + q], p);
      }
      p += __shfl_xor(p, 1);
      p += __shfl_xor(p, 2);
      p += __shfl_xor(p, 4);
      p += __shfl_xor(p, 8);
      long e = base + 16 * (2 * it2);
      if (j == 0 && e < E_TOT) out[e] = 1.f / (1.f + __expf(-(p + b2v)));
    }
    {
      long eN = CLAMP_E(2 * it2 + 3);
      int rN = eli[eN], cN = eli[E_TOT + eN];
      uA0 = *(const short8*)(U + (long)rB * 256 + 8 * j);
      uA1 = *(const short8*)(U + (long)rB * 256 + 128 + 8 * j);
      vA0 = *(const short8*)(V + (long)cB * 256 + 8 * j);
      vA1 = *(const short8*)(V + (long)cB * 256 + 128 + 8 * j);
      rB = rN; cB = cN;
      float p = 0.f;
#pragma unroll
      for (int q = 0; q < 8; ++q) {
        float a0 = bf2f((unsigned short)uB0[q]) + bf2f((unsigned short)vB0[q]);
        float a1 = bf2f((unsigned short)uB1[q]) + bf2f((unsigned short)vB1[q]);
        p = fmaf(fmaxf(a0, 0.f), w2v[q], p);
        p = fmaf(fmaxf(a1, 0.f), w2v[8 + q], p);
      }
      p += __shfl_xor(p, 1);
      p += __shfl_xor(p, 2);
      p += __shfl_xor(p, 4);
      p += __shfl_xor(p, 8);
      long e = base + 16 * (2 * it2 + 1);
      if (j == 0 && e < E_TOT) out[e] = 1.f / (1.f + __expf(-(p + b2v)));
    }
  }
#undef CLAMP_E
}

extern "C" void kernel_launch(void* const* d_in, const int* in_sizes, int n_in,
                              void* d_out, int out_size, void* d_ws,
                              size_t ws_size, hipStream_t stream) {
  const float* zsrc = (const float*)d_in[0];
  const float* zdst = (const float*)d_in[1];
  const int* eli = (const int*)d_in[2];
  const float* w1 = (const float*)d_in[3];
  const float* b1 = (const float*)d_in[4];
  const float* w2 = (const float*)d_in[5];
  const float* b2 = (const float*)d_in[6];
  float* out = (float*)d_out;

  const size_t uv_bytes = (size_t)N_NODES * 256 * 2;  // 51.2 MB each
  unsigned short* U = (unsigned short*)d_ws;
  unsigned short* V = (unsigned short*)((char*)d_ws + uv_bytes);
  unsigned short* w1r2 = (unsigned short*)((char*)d_ws + 2 * uv_bytes);

  k_repack_w1h<<<512, 256, 0, stream>>>(w1, w1r2);
  k_node_gemm<<<512, 512, 0, stream>>>(zsrc, zdst, w1r2, b1, U, V);
  int nbe = (E_TOT + 16 * EK_ITER - 1) / (16 * EK_ITER);
  k_edge<<<nbe, 256, 0, stream>>>(U, V, eli, w2, b2, out);
}

// Round 18
// 137.911 us; speedup vs baseline: 1.0424x; 1.0109x over previous
//
#include <hip/hip_runtime.h>
#include <hip/hip_bf16.h>

#define E_TOT 500000
#define N_NODES 100000
#define NUNITS_H 3125   // 32-row units per half (3125*32 = 100000)
#define SRD 128         // blocks per half (grid 256)

typedef __attribute__((ext_vector_type(16))) float f32x16;
typedef __attribute__((ext_vector_type(8))) short short8;
typedef __attribute__((ext_vector_type(4))) float f32x4;

__device__ __forceinline__ unsigned short f2bf(float f) {
  union { float f; unsigned u; } x; x.f = f;
  unsigned r = x.u + 0x7fffu + ((x.u >> 16) & 1u);
  return (unsigned short)(r >> 16);
}

__device__ __forceinline__ float bf2f(unsigned short s) {
  union { unsigned u; float f; } x; x.u = ((unsigned)s) << 16;
  return x.f;
}

__device__ __forceinline__ short cvt1(float f) {
  __hip_bfloat16 h = __float2bfloat16(f);  // RNE; pairs fuse to v_cvt_pk
  union { __hip_bfloat16 h; short s; } u; u.h = h;
  return u.s;
}

__device__ __forceinline__ void gl_lds16(const void* g, void* l) {
  __builtin_amdgcn_global_load_lds(
      (const __attribute__((address_space(1))) void*)g,
      (__attribute__((address_space(3))) void*)l, 16, 0, 0);
}

// w1 (f32 [256][512]) -> w1r2 bf16 [half][kseg=0..31][n=0..255][j=0..7]
__global__ void k_repack_w1h(const float* __restrict__ w1,
                             unsigned short* __restrict__ w1r2) {
  int o = blockIdx.x * 256 + threadIdx.x;  // 131072 total
  int half = o >> 16;
  int kb = (o >> 11) & 31;
  int n = (o >> 3) & 255;
  int j = o & 7;
  w1r2[o] = f2bf(w1[n * 512 + half * 256 + kb * 8 + j]);
}

// U'[n] = zsrc[n] @ W1s^T + b1 (half 0) ; V[n] = zdst[n] @ W1d^T (half 1)
// v17 = v16 with fixed STAGE rows (wv*4+q) and correct counted vmcnt(8).
// Triple-buffered gl_lds A staging (depth-2 structurally in flight),
// B frags in AGPRs, 2 non-draining barriers/unit, full-line stores.
__global__ __launch_bounds__(512, 1) void k_node_gemm(
    const float* __restrict__ zsrc, const float* __restrict__ zdst,
    const unsigned short* __restrict__ w1r2, const float* __restrict__ b1,
    unsigned short* __restrict__ Uo, unsigned short* __restrict__ Vo) {
  // 3 x 32KB A f32 buffers + 16KB Ct = 112KB
  __shared__ __align__(16) char smem[114688];
  unsigned short* Ct = (unsigned short*)(smem + 98304);

  const int half = blockIdx.x >> 7;   // 128 blocks per half
  const int bh = blockIdx.x & 127;
  const float* Z = half ? zdst : zsrc;
  unsigned short* O = half ? Vo : Uo;

  const unsigned tid = threadIdx.x;
  const unsigned l = tid & 63u;
  const unsigned wv = tid >> 6;   // wave 0..7 -> cols wv*32..wv*32+31
  const unsigned l31 = l & 31u;
  const unsigned hi = l >> 5;
  const unsigned xr = (l31 & 7u) << 4;  // read-side XOR swizzle

  // ---- B fragments: 16 x short8, loaded once (parked in AGPRs) ----
  short8 brg[16];
  {
    const unsigned short* bb = w1r2 + (unsigned)half * 65536u;
#pragma unroll
    for (int k = 0; k < 16; ++k) {
      unsigned ks = (unsigned)k * 2u + hi;
      brg[k] = *(const short8*)(bb + (ks * 256u + wv * 32u + l31) * 8u);
      asm volatile("" : "+v"(brg[k]));  // opacity: no re-materialization
    }
  }

  const float bi = half ? 0.f : b1[wv * 32u + l31];

  // Stage unit uu (32 rows x 1KB f32) into buffer bf (0/1/2); wave stages
  // rows wv*4+q (q=0..3), one full 1KB row per gl_lds sweep (64 lanes x 16B).
  // Source pre-swizzled: LDS[row*1024+b] = global[row*1024+(b^((row&7)<<4))]
#define STAGE(uu, bf)                                                     \
  {                                                                       \
    int uc_ = (uu); if (uc_ >= NUNITS_H) uc_ = NUNITS_H - 1;              \
    const char* src_ = (const char*)(Z + (long)uc_ * 32 * 256);           \
    char* dst_ = smem + (unsigned)(bf)*32768u;                            \
    _Pragma("unroll") for (int q = 0; q < 4; ++q) {                       \
      unsigned row_ = wv * 4u + (unsigned)q;                              \
      unsigned off_ = row_ * 1024u;                                       \
      unsigned so_ = off_ + ((l * 16u) ^ ((row_ & 7u) << 4));             \
      gl_lds16(src_ + so_, dst_ + off_);                                  \
    }                                                                     \
  }

  int u = bh;
  // prologue: S(u)->b0, S(u+S)->b1; vmcnt(4) ensures S(u) complete
  STAGE(u, 0);
  STAGE(u + SRD, 1);
  asm volatile("s_waitcnt vmcnt(4)" ::: "memory");
  __builtin_amdgcn_s_barrier();

  int bufc = 0;
  for (; u < NUNITS_H; u += SRD) {
    int bn = bufc + 2; if (bn >= 3) bn -= 3;
    STAGE(u + 2 * SRD, bn);             // depth-2 stays in flight
    __builtin_amdgcn_sched_barrier(0);
    // per-wave ops younger than S(u) end: <=2 stores + 4 + 2 + 4 = 12 max;
    // vmcnt(8) guarantees S(u) (and prev stores) complete at every iter,
    // while S(u+2S) and >=half of S(u+S) remain in flight.
    asm volatile("s_waitcnt vmcnt(8)" ::: "memory");
    __builtin_amdgcn_s_barrier();

    const char* Ab = smem + (unsigned)bufc * 32768u;
    f32x16 acc = {0.f, 0.f, 0.f, 0.f, 0.f, 0.f, 0.f, 0.f,
                  0.f, 0.f, 0.f, 0.f, 0.f, 0.f, 0.f, 0.f};
#pragma unroll
    for (int kk = 0; kk < 16; ++kk) {
      unsigned c0 = (unsigned)kk * 64u + hi * 32u;
      f32x4 a0 = *(const f32x4*)(Ab + l31 * 1024u + (c0 ^ xr));
      f32x4 a1 = *(const f32x4*)(Ab + l31 * 1024u + ((c0 + 16u) ^ xr));
      short8 af;
      af[0] = cvt1(a0.x); af[1] = cvt1(a0.y);
      af[2] = cvt1(a0.z); af[3] = cvt1(a0.w);
      af[4] = cvt1(a1.x); af[5] = cvt1(a1.y);
      af[6] = cvt1(a1.z); af[7] = cvt1(a1.w);
      acc = __builtin_amdgcn_mfma_f32_32x32x16_bf16(af, brg[kk], acc, 0, 0, 0);
    }

    // C tile -> LDS; only lgkmcnt drained (loads/stores stay in flight)
#pragma unroll
    for (int r = 0; r < 16; ++r) {
      unsigned row32 = (unsigned)((r & 3) + 8 * (r >> 2)) + 4u * hi;
      Ct[row32 * 256u + wv * 32u + l31] = f2bf(acc[r] + bi);
    }
    asm volatile("s_waitcnt lgkmcnt(0)" ::: "memory");
    __builtin_amdgcn_s_barrier();

    // full-line stores (fire-and-forget)
    {
      const long gbase = (long)u * 32 * 256;
#pragma unroll
      for (int p = 0; p < 2; ++p) {
        unsigned s = (unsigned)p * 512u + tid;
        unsigned row = s >> 5;
        unsigned seg = s & 31u;
        short8 vv = *(const short8*)&Ct[row * 256u + seg * 8u];
        *(short8*)(O + gbase + row * 256u + seg * 8u) = vv;
      }
    }
    bufc = (bufc == 2) ? 0 : bufc + 1;
  }
#undef STAGE
}

// per edge: out = sigmoid( w2 . relu(U'[row] + V[col]) + b2 )
// 3-stage pipeline: idx(e+2) || rows(e+1) || compute(e)
#define EK_ITER 16
__global__ __launch_bounds__(256, 6) void k_edge(
    const unsigned short* __restrict__ U, const unsigned short* __restrict__ V,
    const int* __restrict__ eli, const float* __restrict__ w2,
    const float* __restrict__ b2, float* __restrict__ out) {
  const int tid = threadIdx.x;
  const int g = tid >> 4;
  const int j = tid & 15;
  float w2v[16];
#pragma unroll
  for (int q = 0; q < 8; ++q) {
    w2v[q] = w2[8 * j + q];
    w2v[8 + q] = w2[128 + 8 * j + q];
  }
  const float b2v = b2[0];
  const long base = (long)blockIdx.x * (16 * EK_ITER) + g;

#define CLAMP_E(k) \
  (((base + 16 * (k)) < E_TOT) ? (base + 16 * (k)) : (long)(E_TOT - 1))

  long eP = CLAMP_E(0);
  int rA = eli[eP], cA = eli[E_TOT + eP];
  long eQ = CLAMP_E(1);
  int rB = eli[eQ], cB = eli[E_TOT + eQ];
  short8 uA0 = *(const short8*)(U + (long)rA * 256 + 8 * j);
  short8 uA1 = *(const short8*)(U + (long)rA * 256 + 128 + 8 * j);
  short8 vA0 = *(const short8*)(V + (long)cA * 256 + 8 * j);
  short8 vA1 = *(const short8*)(V + (long)cA * 256 + 128 + 8 * j);
  short8 uB0, uB1, vB0, vB1;

#pragma unroll
  for (int it2 = 0; it2 < EK_ITER / 2; ++it2) {
    {
      long eN = CLAMP_E(2 * it2 + 2);
      int rN = eli[eN], cN = eli[E_TOT + eN];
      uB0 = *(const short8*)(U + (long)rB * 256 + 8 * j);
      uB1 = *(const short8*)(U + (long)rB * 256 + 128 + 8 * j);
      vB0 = *(const short8*)(V + (long)cB * 256 + 8 * j);
      vB1 = *(const short8*)(V + (long)cB * 256 + 128 + 8 * j);
      rB = rN; cB = cN;
      float p = 0.f;
#pragma unroll
      for (int q = 0; q < 8; ++q) {
        float a0 = bf2f((unsigned short)uA0[q]) + bf2f((unsigned short)vA0[q]);
        float a1 = bf2f((unsigned short)uA1[q]) + bf2f((unsigned short)vA1[q]);
        p = fmaf(fmaxf(a0, 0.f), w2v[q], p);
        p = fmaf(fmaxf(a1, 0.f), w2v[8 + q], p);
      }
      p += __shfl_xor(p, 1);
      p += __shfl_xor(p, 2);
      p += __shfl_xor(p, 4);
      p += __shfl_xor(p, 8);
      long e = base + 16 * (2 * it2);
      if (j == 0 && e < E_TOT) out[e] = 1.f / (1.f + __expf(-(p + b2v)));
    }
    {
      long eN = CLAMP_E(2 * it2 + 3);
      int rN = eli[eN], cN = eli[E_TOT + eN];
      uA0 = *(const short8*)(U + (long)rB * 256 + 8 * j);
      uA1 = *(const short8*)(U + (long)rB * 256 + 128 + 8 * j);
      vA0 = *(const short8*)(V + (long)cB * 256 + 8 * j);
      vA1 = *(const short8*)(V + (long)cB * 256 + 128 + 8 * j);
      rB = rN; cB = cN;
      float p = 0.f;
#pragma unroll
      for (int q = 0; q < 8; ++q) {
        float a0 = bf2f((unsigned short)uB0[q]) + bf2f((unsigned short)vB0[q]);
        float a1 = bf2f((unsigned short)uB1[q]) + bf2f((unsigned short)vB1[q]);
        p = fmaf(fmaxf(a0, 0.f), w2v[q], p);
        p = fmaf(fmaxf(a1, 0.f), w2v[8 + q], p);
      }
      p += __shfl_xor(p, 1);
      p += __shfl_xor(p, 2);
      p += __shfl_xor(p, 4);
      p += __shfl_xor(p, 8);
      long e = base + 16 * (2 * it2 + 1);
      if (j == 0 && e < E_TOT) out[e] = 1.f / (1.f + __expf(-(p + b2v)));
    }
  }
#undef CLAMP_E
}

extern "C" void kernel_launch(void* const* d_in, const int* in_sizes, int n_in,
                              void* d_out, int out_size, void* d_ws,
                              size_t ws_size, hipStream_t stream) {
  const float* zsrc = (const float*)d_in[0];
  const float* zdst = (const float*)d_in[1];
  const int* eli = (const int*)d_in[2];
  const float* w1 = (const float*)d_in[3];
  const float* b1 = (const float*)d_in[4];
  const float* w2 = (const float*)d_in[5];
  const float* b2 = (const float*)d_in[6];
  float* out = (float*)d_out;

  const size_t uv_bytes = (size_t)N_NODES * 256 * 2;  // 51.2 MB each
  unsigned short* U = (unsigned short*)d_ws;
  unsigned short* V = (unsigned short*)((char*)d_ws + uv_bytes);
  unsigned short* w1r2 = (unsigned short*)((char*)d_ws + 2 * uv_bytes);

  k_repack_w1h<<<512, 256, 0, stream>>>(w1, w1r2);
  k_node_gemm<<<256, 512, 0, stream>>>(zsrc, zdst, w1r2, b1, U, V);
  int nbe = (E_TOT + 16 * EK_ITER - 1) / (16 * EK_ITER);
  k_edge<<<nbe, 256, 0, stream>>>(U, V, eli, w2, b2, out);
}